// Round 5
// baseline (297.189 us; speedup 1.0000x reference)
//
#include <hip/hip_runtime.h>
#include <hip/hip_bf16.h>
#include <math.h>

typedef __hip_bfloat16 bf16;
typedef __attribute__((ext_vector_type(4))) float f32x4;
typedef __attribute__((ext_vector_type(8))) short bf16x8s;

#define T_SEQ 4096
#define MFMA16(a, b, c) __builtin_amdgcn_mfma_f32_16x16x32_bf16(a, b, c, 0, 0, 0)

static __device__ __forceinline__ float bf2f(short u) {
    return __uint_as_float(((unsigned int)(unsigned short)u) << 16);
}
static __device__ __forceinline__ short f2bf(float f) {
    bf16 h = __float2bfloat16(f);
    union { bf16 b; short s; } c; c.b = h; return c.s;
}
static __device__ __forceinline__ int swz_f(int r) { return (r & 7) ^ (r >> 3); }

// ---------------- f32 -> bf16 conversion (vectorized) ----------------
__global__ void cvt_f32_bf16(const float* __restrict__ src, bf16* __restrict__ dst, int n8) {
    int i = blockIdx.x * 256 + threadIdx.x;
    if (i >= n8) return;
    f32x4 a = ((const f32x4*)src)[(size_t)i * 2];
    f32x4 b = ((const f32x4*)src)[(size_t)i * 2 + 1];
    union { bf16 h[8]; uint4 u; } p;
    p.h[0] = __float2bfloat16(a.x); p.h[1] = __float2bfloat16(a.y);
    p.h[2] = __float2bfloat16(a.z); p.h[3] = __float2bfloat16(a.w);
    p.h[4] = __float2bfloat16(b.x); p.h[5] = __float2bfloat16(b.y);
    p.h[6] = __float2bfloat16(b.z); p.h[7] = __float2bfloat16(b.w);
    ((uint4*)dst)[i] = p.u;
}

// ============ 256x256 tile, BK=64, 8-wave deep-pipelined bf16 GEMM ============
// C[M,N] = A[M,K] @ B[N,K]^T. 4 phases/K-tile, counted vmcnt(4), T5 setprio.
// MODE 0: N=3072 qkv -> Q (raw), K (exp), V (raw) bf16 [M,1024]; LDS-staged
//         coalesced epilogue (reuses staging LDS).
// MODE 1: f32 direct output.
// XCD-chunked bijective block swizzle (grid size divisible by 8).
template<int MODE>
__global__ __launch_bounds__(512, 2)
void gemm256(const bf16* __restrict__ A, const bf16* __restrict__ Bm,
             int K, int N,
             bf16* __restrict__ out0, bf16* __restrict__ out1, bf16* __restrict__ out2,
             float* __restrict__ outf)
{
    __shared__ __align__(16) short SMEM[65536];   // 128 KiB: As | Bs staging, then epilogue
    const int tid  = threadIdx.x;
    const int l    = tid & 63;
    const int wid  = tid >> 6;           // 0..7
    const int wr   = wid >> 2;           // 0..1 : M-wave (128 rows each)
    const int wc   = wid & 3;            // 0..3 : N-wave (64 cols each)

    // XCD-chunked swizzle: each XCD gets a contiguous chunk of row-panels
    const int nwg  = gridDim.x * gridDim.y;
    const int flat = blockIdx.y * gridDim.x + blockIdx.x;
    const int swzb = (flat & 7) * (nwg >> 3) + (flat >> 3);
    const int bx   = swzb % gridDim.x;
    const int by   = swzb / gridDim.x;

    const int brow = by * 256;
    const int bcol = bx * 256;
    const int nkt  = K >> 6;

    const bf16* Ab = A  + (size_t)brow * K;
    const bf16* Bb = Bm + (size_t)bcol * K;
    const int srow   = tid >> 2;         // staging row 0..127
    const int schunk = tid & 3;

    // staging layout: As at SMEM[0], Bs at SMEM[32768]; [buf][khalf] strides 8192
#define STAGE(isB, srcp, buf, kh, kt)                                             \
    {                                                                             \
        _Pragma("unroll")                                                         \
        for (int j = 0; j < 2; ++j) {                                             \
            int row = j * 128 + srow;                                             \
            int cs  = schunk ^ ((row >> 1) & 3);                                  \
            const bf16* g = srcp + (size_t)row * K + (kt) * 64 + (kh) * 32 + cs * 8; \
            __builtin_amdgcn_global_load_lds(                                     \
                (const __attribute__((address_space(1))) void*)g,                 \
                (__attribute__((address_space(3))) void*)&SMEM[(isB) * 32768 + ((buf) * 2 + (kh)) * 8192 + (j * 512 + tid) * 8], \
                16, 0, 0);                                                        \
        }                                                                         \
    }
#define RDA(buf, s, m_) (*(const bf16x8s*)&SMEM[((buf) * 2 + (s)) * 8192 + (wr * 128 + (m_) * 16 + (l & 15)) * 32 + (((l >> 4) ^ (((wr * 128 + (m_) * 16 + (l & 15)) >> 1) & 3)) * 8)])
#define RDB(buf, s, n_) (*(const bf16x8s*)&SMEM[32768 + ((buf) * 2 + (s)) * 8192 + (wc * 64 + (n_) * 16 + (l & 15)) * 32 + (((l >> 4) ^ (((wc * 64 + (n_) * 16 + (l & 15)) >> 1) & 3)) * 8)])

    f32x4 acc[8][4];
#pragma unroll
    for (int m = 0; m < 8; ++m)
#pragma unroll
        for (int n = 0; n < 4; ++n) acc[m][n] = (f32x4){0.f, 0.f, 0.f, 0.f};

    // ---- prologue: stage tile 0 fully; complete k0 halves ----
    STAGE(0, Ab, 0, 0, 0);
    STAGE(1, Bb, 0, 0, 0);
    STAGE(0, Ab, 0, 1, 0);
    STAGE(1, Bb, 0, 1, 0);
    asm volatile("s_waitcnt vmcnt(4)" ::: "memory");
    __builtin_amdgcn_s_barrier();

    for (int t = 0; t < nkt; ++t) {
        const int cur = t & 1, nxt = cur ^ 1;
        const bool pf = (t + 1 < nkt);
        bf16x8s bfr[4], afr[4];

        // ---------- phase 0: ksub0, m0-3 ----------
#pragma unroll
        for (int n = 0; n < 4; ++n) bfr[n] = RDB(cur, 0, n);
#pragma unroll
        for (int m = 0; m < 4; ++m) afr[m] = RDA(cur, 0, m);
        if (pf) STAGE(0, Ab, nxt, 0, t + 1);
        __builtin_amdgcn_s_barrier();
        asm volatile("s_waitcnt lgkmcnt(0)" ::: "memory");
        __builtin_amdgcn_sched_barrier(0);
        __builtin_amdgcn_s_setprio(1);
#pragma unroll
        for (int m = 0; m < 4; ++m)
#pragma unroll
            for (int n = 0; n < 4; ++n) acc[m][n] = MFMA16(afr[m], bfr[n], acc[m][n]);
        __builtin_amdgcn_s_setprio(0);
        __builtin_amdgcn_s_barrier();

        // ---------- phase 1: ksub0, m4-7 ----------
#pragma unroll
        for (int m = 0; m < 4; ++m) afr[m] = RDA(cur, 0, m + 4);
        if (pf) STAGE(1, Bb, nxt, 0, t + 1);
        asm volatile("s_waitcnt vmcnt(4)" ::: "memory");
        __builtin_amdgcn_s_barrier();
        asm volatile("s_waitcnt lgkmcnt(0)" ::: "memory");
        __builtin_amdgcn_sched_barrier(0);
        __builtin_amdgcn_s_setprio(1);
#pragma unroll
        for (int m = 0; m < 4; ++m)
#pragma unroll
            for (int n = 0; n < 4; ++n) acc[m + 4][n] = MFMA16(afr[m], bfr[n], acc[m + 4][n]);
        __builtin_amdgcn_s_setprio(0);
        __builtin_amdgcn_s_barrier();

        // ---------- phase 2: ksub1, m0-3 ----------
#pragma unroll
        for (int n = 0; n < 4; ++n) bfr[n] = RDB(cur, 1, n);
#pragma unroll
        for (int m = 0; m < 4; ++m) afr[m] = RDA(cur, 1, m);
        if (pf) STAGE(0, Ab, nxt, 1, t + 1);
        __builtin_amdgcn_s_barrier();
        asm volatile("s_waitcnt lgkmcnt(0)" ::: "memory");
        __builtin_amdgcn_sched_barrier(0);
        __builtin_amdgcn_s_setprio(1);
#pragma unroll
        for (int m = 0; m < 4; ++m)
#pragma unroll
            for (int n = 0; n < 4; ++n) acc[m][n] = MFMA16(afr[m], bfr[n], acc[m][n]);
        __builtin_amdgcn_s_setprio(0);
        __builtin_amdgcn_s_barrier();

        // ---------- phase 3: ksub1, m4-7 ----------
#pragma unroll
        for (int m = 0; m < 4; ++m) afr[m] = RDA(cur, 1, m + 4);
        if (pf) STAGE(1, Bb, nxt, 1, t + 1);
        asm volatile("s_waitcnt vmcnt(4)" ::: "memory");
        __builtin_amdgcn_s_barrier();
        asm volatile("s_waitcnt lgkmcnt(0)" ::: "memory");
        __builtin_amdgcn_sched_barrier(0);
        __builtin_amdgcn_s_setprio(1);
#pragma unroll
        for (int m = 0; m < 4; ++m)
#pragma unroll
            for (int n = 0; n < 4; ++n) acc[m + 4][n] = MFMA16(afr[m], bfr[n], acc[m + 4][n]);
        __builtin_amdgcn_s_setprio(0);
        __builtin_amdgcn_s_barrier();
    }

    if (MODE == 1) {
        // direct f32 stores (64B segments per 16 lanes)
#pragma unroll
        for (int m = 0; m < 8; ++m) {
            int row = brow + wr * 128 + m * 16 + ((l >> 4) << 2);
#pragma unroll
            for (int n = 0; n < 4; ++n) {
                int col = bcol + wc * 64 + n * 16 + (l & 15);
#pragma unroll
                for (int r = 0; r < 4; ++r)
                    outf[(size_t)(row + r) * N + col] = acc[m][n][r];
            }
        }
    } else {
        // LDS-staged coalesced bf16 epilogue (2 halves of 128 rows), expf for region 1
        const int region = bcol >> 10;
        const int cbase  = bcol & 1023;
        bf16* dst = (region == 0) ? out0 : (region == 1) ? out1 : out2;
#pragma unroll
        for (int h = 0; h < 2; ++h) {
            if (wr == h) {
#pragma unroll
                for (int m = 0; m < 8; ++m) {
                    int rl = m * 16 + ((l >> 4) << 2);
#pragma unroll
                    for (int n = 0; n < 4; ++n) {
                        int col = wc * 64 + n * 16 + (l & 15);
#pragma unroll
                        for (int r = 0; r < 4; ++r) {
                            float v = acc[m][n][r];
                            if (region == 1) v = __expf(v);
                            SMEM[(rl + r) * 264 + col] = f2bf(v);
                        }
                    }
                }
            }
            __syncthreads();
            {
                int row = tid >> 2;
                int cc  = (tid & 3) * 64;
                size_t gb = (size_t)(brow + h * 128 + row) * 1024 + cbase + cc;
#pragma unroll
                for (int j = 0; j < 8; ++j) {
                    bf16x8s vv = *(const bf16x8s*)&SMEM[row * 264 + cc + j * 8];
                    *(bf16x8s*)&dst[gb + j * 8] = vv;
                }
            }
            __syncthreads();
        }
    }
#undef STAGE
#undef RDA
#undef RDB
}

// ---------------- per-bucket K-sum (f32) and K^T V outer product (MFMA, bf16 out) ----------------
__global__ __launch_bounds__(256)
void bucket_kv(const bf16* __restrict__ Kb, const bf16* __restrict__ Vb,
               bf16* __restrict__ ctxb, float* __restrict__ ksum)
{
    __shared__ __align__(16) short k_t[64 * 64];   // [d][s] swizzled
    __shared__ __align__(16) short v_t[64 * 64];   // [e][s] swizzled
    __shared__ __align__(16) float ct[64 * 68];    // [e][d] padded f32
    const int bid = blockIdx.x;
    const int bh = bid >> 6, n = bid & 63;
    const int b = bh >> 4, h = bh & 15;
    const size_t rowbase = (size_t)(b * T_SEQ + n * 64) * 1024 + h * 64;
    const int tid = threadIdx.x;

#pragma unroll
    for (int half = 0; half < 2; ++half) {
        int s  = (tid >> 3) + half * 32;
        int dc = tid & 7;
        bf16x8s kv = *(const bf16x8s*)&Kb[rowbase + (size_t)s * 1024 + dc * 8];
        bf16x8s vv = *(const bf16x8s*)&Vb[rowbase + (size_t)s * 1024 + dc * 8];
        int sc = s >> 3, slo = s & 7;
#pragma unroll
        for (int u = 0; u < 8; ++u) {
            int d = dc * 8 + u;
            int addr = d * 64 + (((sc) ^ swz_f(d)) << 3) + slo;
            k_t[addr] = ((short*)&kv)[u];
            v_t[addr] = ((short*)&vv)[u];
        }
    }
    __syncthreads();

    const int l = tid & 63, w = tid >> 6;

    if (tid < 64) {
        int d = tid;
        float s = 0.f;
#pragma unroll
        for (int c = 0; c < 8; ++c) {
            bf16x8s kk = *(const bf16x8s*)&k_t[d * 64 + ((c ^ swz_f(d)) << 3)];
#pragma unroll
            for (int u = 0; u < 8; ++u) s += bf2f(((short*)&kk)[u]);
        }
        ksum[(size_t)bid * 64 + d] = s;
    }

    f32x4 acc[4];
#pragma unroll
    for (int i = 0; i < 4; ++i) acc[i] = (f32x4){0.f, 0.f, 0.f, 0.f};
    bf16x8s afr[2], bfr[2][4];
#pragma unroll
    for (int kk = 0; kk < 2; ++kk) {
        int cc = kk * 4 + (l >> 4);
        int r = w * 16 + (l & 15);
        afr[kk] = *(const bf16x8s*)&k_t[r * 64 + ((cc ^ swz_f(r)) << 3)];
#pragma unroll
        for (int n4 = 0; n4 < 4; ++n4) {
            int e = n4 * 16 + (l & 15);
            bfr[kk][n4] = *(const bf16x8s*)&v_t[e * 64 + ((cc ^ swz_f(e)) << 3)];
        }
    }
#pragma unroll
    for (int kk = 0; kk < 2; ++kk)
#pragma unroll
        for (int n4 = 0; n4 < 4; ++n4)
            acc[n4] = MFMA16(afr[kk], bfr[kk][n4], acc[n4]);

#pragma unroll
    for (int n4 = 0; n4 < 4; ++n4) {
        int e = n4 * 16 + (l & 15);
        int d0 = w * 16 + ((l >> 4) << 2);
        *(f32x4*)&ct[e * 68 + d0] = acc[n4];
    }
    __syncthreads();

#pragma unroll
    for (int j = 0; j < 2; ++j) {
        int i = tid + 256 * j;
        int e = i >> 3, d0 = (i & 7) * 8;
        f32x4 lo = *(const f32x4*)&ct[e * 68 + d0];
        f32x4 hi = *(const f32x4*)&ct[e * 68 + d0 + 4];
        union { short h[8]; uint4 u; } p;
        p.h[0] = f2bf(lo.x); p.h[1] = f2bf(lo.y); p.h[2] = f2bf(lo.z); p.h[3] = f2bf(lo.w);
        p.h[4] = f2bf(hi.x); p.h[5] = f2bf(hi.y); p.h[6] = f2bf(hi.z); p.h[7] = f2bf(hi.w);
        ((uint4*)&ctxb[(size_t)bid * 4096])[i] = p.u;
    }
}

// ---------------- exclusive cumsum over buckets ----------------
__global__ void cumsum_excl(const bf16* __restrict__ ctxb, const float* __restrict__ ksum,
                            bf16* __restrict__ ctp, float* __restrict__ ksump)
{
    const int bh = blockIdx.y;
    if (blockIdx.x == 4) {
        int d = threadIdx.x;
        if (d >= 64) return;
        float run = 0.f;
        for (int j = 0; j < 64; ++j) {
            size_t idx = (size_t)(bh * 64 + j) * 64 + d;
            float v = ksum[idx];
            ksump[idx] = run;
            run += v;
        }
        return;
    }
    int e0 = (blockIdx.x * 256 + threadIdx.x) * 4;
    float r0 = 0.f, r1 = 0.f, r2 = 0.f, r3 = 0.f;
    for (int j = 0; j < 64; ++j) {
        size_t idx = (size_t)(bh * 64 + j) * 4096 + e0;
        ushort4 v = *(const ushort4*)&ctxb[idx];
        ushort4 o;
        o.x = (ushort)f2bf(r0); o.y = (ushort)f2bf(r1);
        o.z = (ushort)f2bf(r2); o.w = (ushort)f2bf(r3);
        *(ushort4*)&ctp[idx] = o;
        r0 += bf2f((short)v.x); r1 += bf2f((short)v.y);
        r2 += bf2f((short)v.z); r3 += bf2f((short)v.w);
    }
}

// ---------------- softmax(q) + den + attn = q @ ctx * Dinv (MFMA) ----------------
__global__ __launch_bounds__(256)
void bucket_attn(const bf16* __restrict__ Qb, const bf16* __restrict__ ctp,
                 const float* __restrict__ ksump, bf16* __restrict__ attn)
{
    __shared__ __align__(16) short q_bf[64 * 64];
    __shared__ __align__(16) short ct_bf[64 * 64];
    __shared__ __align__(16) short at_s[64 * 72];
    __shared__ float dinv_s[64];
    __shared__ float ksum_s[64];
    const int bid = blockIdx.x;
    const int bh = bid >> 6, n = bid & 63;
    const int b = bh >> 4, h = bh & 15;
    const size_t rowbase = (size_t)(b * T_SEQ + n * 64) * 1024 + h * 64;
    const int tid = threadIdx.x;
    const int l = tid & 63, w = tid >> 6;

#pragma unroll
    for (int j = 0; j < 2; ++j) {
        int i = tid + 256 * j;
        int e = i >> 3, dc = i & 7;
        bf16x8s cv = *(const bf16x8s*)&ctp[(size_t)bid * 4096 + e * 64 + dc * 8];
        *(bf16x8s*)&ct_bf[e * 64 + ((dc ^ swz_f(e)) << 3)] = cv;
    }
    if (tid < 64) ksum_s[tid] = ksump[(size_t)bid * 64 + tid];
    __syncthreads();

#pragma unroll
    for (int i = 0; i < 16; ++i) {
        int s = w * 16 + i;
        float x = bf2f(*(const short*)&Qb[rowbase + (size_t)s * 1024 + l]);
        float mx = x;
#pragma unroll
        for (int off = 32; off; off >>= 1) mx = fmaxf(mx, __shfl_xor(mx, off));
        float ex = __expf(x - mx);
        float sm = ex;
#pragma unroll
        for (int off = 32; off; off >>= 1) sm += __shfl_xor(sm, off);
        float qv = ex / sm * 0.125f;
        float dp = qv * ksum_s[l];
#pragma unroll
        for (int off = 32; off; off >>= 1) dp += __shfl_xor(dp, off);
        if (l == 0) dinv_s[s] = 1.f / fmaxf(dp, 1e-6f);
        q_bf[s * 64 + ((((l >> 3)) ^ swz_f(s)) << 3) + (l & 7)] = f2bf(qv);
    }
    __syncthreads();

    f32x4 acc[4];
#pragma unroll
    for (int i = 0; i < 4; ++i) acc[i] = (f32x4){0.f, 0.f, 0.f, 0.f};
    bf16x8s afr[2], bfr[2][4];
#pragma unroll
    for (int kk = 0; kk < 2; ++kk) {
        int cc = kk * 4 + (l >> 4);
        int r = w * 16 + (l & 15);
        afr[kk] = *(const bf16x8s*)&q_bf[r * 64 + ((cc ^ swz_f(r)) << 3)];
#pragma unroll
        for (int n4 = 0; n4 < 4; ++n4) {
            int e = n4 * 16 + (l & 15);
            bfr[kk][n4] = *(const bf16x8s*)&ct_bf[e * 64 + ((cc ^ swz_f(e)) << 3)];
        }
    }
#pragma unroll
    for (int kk = 0; kk < 2; ++kk)
#pragma unroll
        for (int n4 = 0; n4 < 4; ++n4)
            acc[n4] = MFMA16(afr[kk], bfr[kk][n4], acc[n4]);

#pragma unroll
    for (int n4 = 0; n4 < 4; ++n4) {
        int e = n4 * 16 + (l & 15);
#pragma unroll
        for (int r = 0; r < 4; ++r) {
            int s = w * 16 + ((l >> 4) << 2) + r;
            at_s[s * 72 + e] = f2bf(acc[n4][r] * dinv_s[s]);
        }
    }
    __syncthreads();

#pragma unroll
    for (int j = 0; j < 2; ++j) {
        int i = tid + 256 * j;
        int s = i >> 3, c = i & 7;
        bf16x8s v = *(const bf16x8s*)&at_s[s * 72 + c * 8];
        *(bf16x8s*)&attn[rowbase + (size_t)s * 1024 + c * 8] = v;
    }
}

// ---------------- launch ----------------
extern "C" void kernel_launch(void* const* d_in, const int* in_sizes, int n_in,
                              void* d_out, int out_size, void* d_ws, size_t ws_size,
                              hipStream_t stream)
{
    const float* x    = (const float*)d_in[0];
    const float* Wqkv = (const float*)d_in[1];
    const float* Wout = (const float*)d_in[2];

    char* ws = (char*)d_ws;
    size_t off = 0;
    auto alloc = [&](size_t bytes) { void* p = ws + off; off += (bytes + 255) & ~(size_t)255; return p; };
    bf16*  xb    = (bf16*)alloc((size_t)16384 * 1024 * 2);
    bf16*  wqkvb = (bf16*)alloc((size_t)3072 * 1024 * 2);
    bf16*  woutb = (bf16*)alloc((size_t)1024 * 1024 * 2);
    bf16*  Qb    = (bf16*)alloc((size_t)16384 * 1024 * 2);
    bf16*  Kb    = (bf16*)alloc((size_t)16384 * 1024 * 2);
    bf16*  Vb    = (bf16*)alloc((size_t)16384 * 1024 * 2);
    bf16*  ctxb  = (bf16*)alloc((size_t)4096 * 4096 * 2);
    float* ksum  = (float*)alloc((size_t)4096 * 64 * 4);
    bf16*  ctp   = (bf16*)alloc((size_t)4096 * 4096 * 2);
    float* ksump = (float*)alloc((size_t)4096 * 64 * 4);
    bf16*  attnb = xb;                       // xb dead after GEMM1 -> reuse
    float* outf  = (float*)d_out;

    cvt_f32_bf16<<<dim3(16384 * 1024 / 8 / 256), 256, 0, stream>>>(x, xb, 16384 * 1024 / 8);
    cvt_f32_bf16<<<dim3(3072 * 1024 / 8 / 256), 256, 0, stream>>>(Wqkv, wqkvb, 3072 * 1024 / 8);
    cvt_f32_bf16<<<dim3(1024 * 1024 / 8 / 256), 256, 0, stream>>>(Wout, woutb, 1024 * 1024 / 8);

    gemm256<0><<<dim3(12, 64), 512, 0, stream>>>(xb, wqkvb, 1024, 3072, Qb, Kb, Vb, nullptr);
    bucket_kv<<<dim3(4096), 256, 0, stream>>>(Kb, Vb, ctxb, ksum);
    cumsum_excl<<<dim3(5, 64), 256, 0, stream>>>(ctxb, ksum, ctp, ksump);
    bucket_attn<<<dim3(4096), 256, 0, stream>>>(Qb, ctp, ksump, attnb);
    gemm256<1><<<dim3(4, 64), 512, 0, stream>>>(attnb, woutb, 1024, 1024, nullptr, nullptr, nullptr, outf);
}

// Round 6
// 268.534 us; speedup vs baseline: 1.1067x; 1.1067x over previous
//
#include <hip/hip_runtime.h>
#include <hip/hip_bf16.h>
#include <math.h>

typedef __hip_bfloat16 bf16;
typedef __attribute__((ext_vector_type(4))) float f32x4;
typedef __attribute__((ext_vector_type(8))) short bf16x8s;

#define T_SEQ 4096
#define MFMA16(a, b, c) __builtin_amdgcn_mfma_f32_16x16x32_bf16(a, b, c, 0, 0, 0)
#define AS1 __attribute__((address_space(1)))
#define AS3 __attribute__((address_space(3)))

static __device__ __forceinline__ float bf2f(short u) {
    return __uint_as_float(((unsigned int)(unsigned short)u) << 16);
}
static __device__ __forceinline__ short f2bf(float f) {
    bf16 h = __float2bfloat16(f);
    union { bf16 b; short s; } c; c.b = h; return c.s;
}
static __device__ __forceinline__ int swz_f(int r) { return (r & 7) ^ (r >> 3); }

// ---------------- f32 -> bf16 conversion (vectorized) ----------------
__global__ void cvt_f32_bf16(const float* __restrict__ src, bf16* __restrict__ dst, int n8) {
    int i = blockIdx.x * 256 + threadIdx.x;
    if (i >= n8) return;
    f32x4 a = ((const f32x4*)src)[(size_t)i * 2];
    f32x4 b = ((const f32x4*)src)[(size_t)i * 2 + 1];
    union { bf16 h[8]; uint4 u; } p;
    p.h[0] = __float2bfloat16(a.x); p.h[1] = __float2bfloat16(a.y);
    p.h[2] = __float2bfloat16(a.z); p.h[3] = __float2bfloat16(a.w);
    p.h[4] = __float2bfloat16(b.x); p.h[5] = __float2bfloat16(b.y);
    p.h[6] = __float2bfloat16(b.z); p.h[7] = __float2bfloat16(b.w);
    ((uint4*)dst)[i] = p.u;
}

// ============ 256x256 tile, BK=64, 8-wave deep-pipelined bf16 GEMM ============
// C[M,N] = A[M,K] @ B[N,K]^T. 4 phases/K-tile, counted vmcnt(4), T5 setprio.
// K-loop unrolled x2 (nkt must be even) so buf index is compile-time and ALL
// LDS fragment addresses fold to one per-lane base + ds_read offset:imm.
// MODE 0: N=3072 qkv -> Q (raw), K (exp), V (raw) bf16 [M,1024], direct stores.
// MODE 1: f32 direct output.
template<int MODE>
__global__ __launch_bounds__(512, 2)
void gemm256(const bf16* __restrict__ A, const bf16* __restrict__ Bm,
             int K, int N,
             bf16* __restrict__ out0, bf16* __restrict__ out1, bf16* __restrict__ out2,
             float* __restrict__ outf)
{
    __shared__ __align__(16) short SMEM[65536];   // A: [buf][kh] @ (buf*2+kh)*8192 ; B: +32768
    const int tid  = threadIdx.x;
    const int l    = tid & 63;
    const int wid  = tid >> 6;
    const int wr   = wid >> 2;           // 0..1
    const int wc   = wid & 3;            // 0..3

    // XCD-chunked bijective swizzle (grid % 8 == 0)
    const int nwg  = gridDim.x * gridDim.y;
    const int flat = blockIdx.y * gridDim.x + blockIdx.x;
    const int swzb = (flat & 7) * (nwg >> 3) + (flat >> 3);
    const int bx   = swzb % gridDim.x;
    const int by   = swzb / gridDim.x;
    const int brow = by * 256;
    const int bcol = bx * 256;
    const int nkt  = K >> 6;             // must be even

    // per-lane LDS fragment bases; swizzle chunk is m/n-independent:
    // chunk = (l>>4) ^ ((row>>1)&3), row = {wr*128|wc*64} + m*16 + (l&15)
    //       = (l>>4) ^ (((l&15)>>1)&3)   [wr*64, wc*32, m*8 all ≡ 0 mod 4]
    const int chnk = (l >> 4) ^ (((l & 15) >> 1) & 3);
    const short* baseA = &SMEM[(wr * 128 + (l & 15)) * 32 + chnk * 8];
    const short* baseB = &SMEM[32768 + (wc * 64 + (l & 15)) * 32 + chnk * 8];
#define RDA(BUF, KH, M_) (*(const bf16x8s*)(baseA + (BUF) * 16384 + (KH) * 8192 + (M_) * 512))
#define RDB(BUF, KH, N_) (*(const bf16x8s*)(baseB + (BUF) * 16384 + (KH) * 8192 + (N_) * 512))

    // staging: thread -> (srow 0..127, chunk), rows srow and srow+128
    const int srow   = tid >> 2;
    const int scs    = (tid & 3) ^ ((srow >> 1) & 3);   // j-independent (128 ≡ 0 mod 4 after >>1 &3)
    const bf16* gA0 = A  + (size_t)(brow + srow) * K + scs * 8;
    const bf16* gA1 = A  + (size_t)(brow + 128 + srow) * K + scs * 8;
    const bf16* gB0 = Bm + (size_t)(bcol + srow) * K + scs * 8;
    const bf16* gB1 = Bm + (size_t)(bcol + 128 + srow) * K + scs * 8;
#define GLL(PTR, KH, BUF, ISB, EXTRA)                                             \
    __builtin_amdgcn_global_load_lds((const AS1 void*)((PTR) + (KH) * 32),        \
        (AS3 void*)&SMEM[(ISB) * 32768 + ((BUF) * 2 + (KH)) * 8192 + (EXTRA) + tid * 8], 16, 0, 0)

    f32x4 acc[8][4];
#pragma unroll
    for (int m = 0; m < 8; ++m)
#pragma unroll
        for (int n = 0; n < 4; ++n) acc[m][n] = (f32x4){0.f, 0.f, 0.f, 0.f};

    // ---- prologue: stage tile 0 (A k0, B k0, A k1, B k1); complete k0 ----
    GLL(gA0, 0, 0, 0, 0);    GLL(gA1, 0, 0, 0, 4096);
    GLL(gB0, 0, 0, 1, 0);    GLL(gB1, 0, 0, 1, 4096);
    GLL(gA0, 1, 0, 0, 0);    GLL(gA1, 1, 0, 0, 4096);
    GLL(gB0, 1, 0, 1, 0);    GLL(gB1, 1, 0, 1, 4096);
    asm volatile("s_waitcnt vmcnt(4)" ::: "memory");
    __builtin_amdgcn_s_barrier();

    // prefetch pointers point at tile tt+1 during BODY(tt)
    const bf16 *pA0 = gA0 + 64, *pA1 = gA1 + 64, *pB0 = gB0 + 64, *pB1 = gB1 + 64;

#define MFMA_BLOCK(ACCOFF)                                                        \
    __builtin_amdgcn_s_barrier();                                                 \
    asm volatile("s_waitcnt lgkmcnt(0)" ::: "memory");                            \
    __builtin_amdgcn_sched_barrier(0);                                            \
    __builtin_amdgcn_s_setprio(1);                                                \
    _Pragma("unroll")                                                             \
    for (int m = 0; m < 4; ++m)                                                   \
        _Pragma("unroll")                                                         \
        for (int n = 0; n < 4; ++n)                                               \
            acc[m + (ACCOFF)][n] = MFMA16(afr[m], bfr[n], acc[m + (ACCOFF)][n]);  \
    __builtin_amdgcn_s_setprio(0);                                                \
    __builtin_amdgcn_s_barrier();

#define BODY(CUR, NXT, TT)                                                        \
    {                                                                             \
        const bool pf = ((TT) + 1 < nkt);                                         \
        bf16x8s afr[4], bfr[4];                                                   \
        /* phase 0: k0, m0-3 ; stage A(k0, t+1) */                                \
        _Pragma("unroll") for (int n = 0; n < 4; ++n) bfr[n] = RDB(CUR, 0, n);    \
        _Pragma("unroll") for (int m = 0; m < 4; ++m) afr[m] = RDA(CUR, 0, m);    \
        if (pf) { GLL(pA0, 0, NXT, 0, 0); GLL(pA1, 0, NXT, 0, 4096); }            \
        MFMA_BLOCK(0)                                                             \
        /* phase 1: k0, m4-7 ; stage B(k0, t+1) ; vmcnt completes k1(t) */        \
        _Pragma("unroll") for (int m = 0; m < 4; ++m) afr[m] = RDA(CUR, 0, m + 4);\
        if (pf) { GLL(pB0, 0, NXT, 1, 0); GLL(pB1, 0, NXT, 1, 4096); }            \
        asm volatile("s_waitcnt vmcnt(4)" ::: "memory");                          \
        MFMA_BLOCK(4)                                                             \
        /* phase 2: k1, m0-3 ; stage A(k1, t+1) */                                \
        _Pragma("unroll") for (int n = 0; n < 4; ++n) bfr[n] = RDB(CUR, 1, n);    \
        _Pragma("unroll") for (int m = 0; m < 4; ++m) afr[m] = RDA(CUR, 1, m);    \
        if (pf) { GLL(pA0, 1, NXT, 0, 0); GLL(pA1, 1, NXT, 0, 4096); }            \
        MFMA_BLOCK(0)                                                             \
        /* phase 3: k1, m4-7 ; stage B(k1, t+1) ; vmcnt completes k0(t+1) */      \
        _Pragma("unroll") for (int m = 0; m < 4; ++m) afr[m] = RDA(CUR, 1, m + 4);\
        if (pf) { GLL(pB0, 1, NXT, 1, 0); GLL(pB1, 1, NXT, 1, 4096); }            \
        asm volatile("s_waitcnt vmcnt(4)" ::: "memory");                          \
        MFMA_BLOCK(4)                                                             \
        pA0 += 64; pA1 += 64; pB0 += 64; pB1 += 64;                               \
    }

    for (int t = 0; t < nkt; t += 2) {
        BODY(0, 1, t)
        BODY(1, 0, t + 1)
    }

    // ---------- epilogue: direct stores; C map col=lane&15, row=(lane>>4)*4+r ----------
    const int region = bcol >> 10;
#pragma unroll
    for (int m = 0; m < 8; ++m) {
        int row = brow + wr * 128 + m * 16 + ((l >> 4) << 2);
#pragma unroll
        for (int n = 0; n < 4; ++n) {
            int col = bcol + wc * 64 + n * 16 + (l & 15);
#pragma unroll
            for (int r = 0; r < 4; ++r) {
                float v = acc[m][n][r];
                size_t rr = (size_t)(row + r);
                if (MODE == 1) {
                    outf[rr * N + col] = v;
                } else {
                    int c = col & 1023;
                    if (region == 0)      out0[rr * 1024 + c] = __float2bfloat16(v);
                    else if (region == 1) out1[rr * 1024 + c] = __float2bfloat16(__expf(v));
                    else                  out2[rr * 1024 + c] = __float2bfloat16(v);
                }
            }
        }
    }
#undef RDA
#undef RDB
#undef GLL
#undef MFMA_BLOCK
#undef BODY
}

// ---------------- per-bucket K-sum (f32) and K^T V outer product (MFMA, bf16 out) ----------------
__global__ __launch_bounds__(256)
void bucket_kv(const bf16* __restrict__ Kb, const bf16* __restrict__ Vb,
               bf16* __restrict__ ctxb, float* __restrict__ ksum)
{
    __shared__ __align__(16) short k_t[64 * 64];   // [d][s] swizzled
    __shared__ __align__(16) short v_t[64 * 64];   // [e][s] swizzled
    __shared__ __align__(16) float ct[64 * 68];    // [e][d] padded f32
    const int bid = blockIdx.x;
    const int bh = bid >> 6, n = bid & 63;
    const int b = bh >> 4, h = bh & 15;
    const size_t rowbase = (size_t)(b * T_SEQ + n * 64) * 1024 + h * 64;
    const int tid = threadIdx.x;

#pragma unroll
    for (int half = 0; half < 2; ++half) {
        int s  = (tid >> 3) + half * 32;
        int dc = tid & 7;
        bf16x8s kv = *(const bf16x8s*)&Kb[rowbase + (size_t)s * 1024 + dc * 8];
        bf16x8s vv = *(const bf16x8s*)&Vb[rowbase + (size_t)s * 1024 + dc * 8];
        int sc = s >> 3, slo = s & 7;
#pragma unroll
        for (int u = 0; u < 8; ++u) {
            int d = dc * 8 + u;
            int addr = d * 64 + (((sc) ^ swz_f(d)) << 3) + slo;
            k_t[addr] = ((short*)&kv)[u];
            v_t[addr] = ((short*)&vv)[u];
        }
    }
    __syncthreads();

    const int l = tid & 63, w = tid >> 6;

    if (tid < 64) {
        int d = tid;
        float s = 0.f;
#pragma unroll
        for (int c = 0; c < 8; ++c) {
            bf16x8s kk = *(const bf16x8s*)&k_t[d * 64 + ((c ^ swz_f(d)) << 3)];
#pragma unroll
            for (int u = 0; u < 8; ++u) s += bf2f(((short*)&kk)[u]);
        }
        ksum[(size_t)bid * 64 + d] = s;
    }

    f32x4 acc[4];
#pragma unroll
    for (int i = 0; i < 4; ++i) acc[i] = (f32x4){0.f, 0.f, 0.f, 0.f};
    bf16x8s afr[2], bfr[2][4];
#pragma unroll
    for (int kk = 0; kk < 2; ++kk) {
        int cc = kk * 4 + (l >> 4);
        int r = w * 16 + (l & 15);
        afr[kk] = *(const bf16x8s*)&k_t[r * 64 + ((cc ^ swz_f(r)) << 3)];
#pragma unroll
        for (int n4 = 0; n4 < 4; ++n4) {
            int e = n4 * 16 + (l & 15);
            bfr[kk][n4] = *(const bf16x8s*)&v_t[e * 64 + ((cc ^ swz_f(e)) << 3)];
        }
    }
#pragma unroll
    for (int kk = 0; kk < 2; ++kk)
#pragma unroll
        for (int n4 = 0; n4 < 4; ++n4)
            acc[n4] = MFMA16(afr[kk], bfr[kk][n4], acc[n4]);

#pragma unroll
    for (int n4 = 0; n4 < 4; ++n4) {
        int e = n4 * 16 + (l & 15);
        int d0 = w * 16 + ((l >> 4) << 2);
        *(f32x4*)&ct[e * 68 + d0] = acc[n4];
    }
    __syncthreads();

#pragma unroll
    for (int j = 0; j < 2; ++j) {
        int i = tid + 256 * j;
        int e = i >> 3, d0 = (i & 7) * 8;
        f32x4 lo = *(const f32x4*)&ct[e * 68 + d0];
        f32x4 hi = *(const f32x4*)&ct[e * 68 + d0 + 4];
        union { short h[8]; uint4 u; } p;
        p.h[0] = f2bf(lo.x); p.h[1] = f2bf(lo.y); p.h[2] = f2bf(lo.z); p.h[3] = f2bf(lo.w);
        p.h[4] = f2bf(hi.x); p.h[5] = f2bf(hi.y); p.h[6] = f2bf(hi.z); p.h[7] = f2bf(hi.w);
        ((uint4*)&ctxb[(size_t)bid * 4096])[i] = p.u;
    }
}

// ---------------- exclusive cumsum over buckets ----------------
__global__ void cumsum_excl(const bf16* __restrict__ ctxb, const float* __restrict__ ksum,
                            bf16* __restrict__ ctp, float* __restrict__ ksump)
{
    const int bh = blockIdx.y;
    if (blockIdx.x == 4) {
        int d = threadIdx.x;
        if (d >= 64) return;
        float run = 0.f;
        for (int j = 0; j < 64; ++j) {
            size_t idx = (size_t)(bh * 64 + j) * 64 + d;
            float v = ksum[idx];
            ksump[idx] = run;
            run += v;
        }
        return;
    }
    int e0 = (blockIdx.x * 256 + threadIdx.x) * 4;
    float r0 = 0.f, r1 = 0.f, r2 = 0.f, r3 = 0.f;
    for (int j = 0; j < 64; ++j) {
        size_t idx = (size_t)(bh * 64 + j) * 4096 + e0;
        ushort4 v = *(const ushort4*)&ctxb[idx];
        ushort4 o;
        o.x = (ushort)f2bf(r0); o.y = (ushort)f2bf(r1);
        o.z = (ushort)f2bf(r2); o.w = (ushort)f2bf(r3);
        *(ushort4*)&ctp[idx] = o;
        r0 += bf2f((short)v.x); r1 += bf2f((short)v.y);
        r2 += bf2f((short)v.z); r3 += bf2f((short)v.w);
    }
}

// ---------------- softmax(q) + den + attn = q @ ctx * Dinv (MFMA) ----------------
__global__ __launch_bounds__(256)
void bucket_attn(const bf16* __restrict__ Qb, const bf16* __restrict__ ctp,
                 const float* __restrict__ ksump, bf16* __restrict__ attn)
{
    __shared__ __align__(16) short q_bf[64 * 64];
    __shared__ __align__(16) short ct_bf[64 * 64];
    __shared__ __align__(16) short at_s[64 * 72];
    __shared__ float dinv_s[64];
    __shared__ float ksum_s[64];
    const int bid = blockIdx.x;
    const int bh = bid >> 6, n = bid & 63;
    const int b = bh >> 4, h = bh & 15;
    const size_t rowbase = (size_t)(b * T_SEQ + n * 64) * 1024 + h * 64;
    const int tid = threadIdx.x;
    const int l = tid & 63, w = tid >> 6;

#pragma unroll
    for (int j = 0; j < 2; ++j) {
        int i = tid + 256 * j;
        int e = i >> 3, dc = i & 7;
        bf16x8s cv = *(const bf16x8s*)&ctp[(size_t)bid * 4096 + e * 64 + dc * 8];
        *(bf16x8s*)&ct_bf[e * 64 + ((dc ^ swz_f(e)) << 3)] = cv;
    }
    if (tid < 64) ksum_s[tid] = ksump[(size_t)bid * 64 + tid];
    __syncthreads();

#pragma unroll
    for (int i = 0; i < 16; ++i) {
        int s = w * 16 + i;
        float x = bf2f(*(const short*)&Qb[rowbase + (size_t)s * 1024 + l]);
        float mx = x;
#pragma unroll
        for (int off = 32; off; off >>= 1) mx = fmaxf(mx, __shfl_xor(mx, off));
        float ex = __expf(x - mx);
        float sm = ex;
#pragma unroll
        for (int off = 32; off; off >>= 1) sm += __shfl_xor(sm, off);
        float qv = ex / sm * 0.125f;
        float dp = qv * ksum_s[l];
#pragma unroll
        for (int off = 32; off; off >>= 1) dp += __shfl_xor(dp, off);
        if (l == 0) dinv_s[s] = 1.f / fmaxf(dp, 1e-6f);
        q_bf[s * 64 + ((((l >> 3)) ^ swz_f(s)) << 3) + (l & 7)] = f2bf(qv);
    }
    __syncthreads();

    f32x4 acc[4];
#pragma unroll
    for (int i = 0; i < 4; ++i) acc[i] = (f32x4){0.f, 0.f, 0.f, 0.f};
    bf16x8s afr[2], bfr[2][4];
#pragma unroll
    for (int kk = 0; kk < 2; ++kk) {
        int cc = kk * 4 + (l >> 4);
        int r = w * 16 + (l & 15);
        afr[kk] = *(const bf16x8s*)&q_bf[r * 64 + ((cc ^ swz_f(r)) << 3)];
#pragma unroll
        for (int n4 = 0; n4 < 4; ++n4) {
            int e = n4 * 16 + (l & 15);
            bfr[kk][n4] = *(const bf16x8s*)&ct_bf[e * 64 + ((cc ^ swz_f(e)) << 3)];
        }
    }
#pragma unroll
    for (int kk = 0; kk < 2; ++kk)
#pragma unroll
        for (int n4 = 0; n4 < 4; ++n4)
            acc[n4] = MFMA16(afr[kk], bfr[kk][n4], acc[n4]);

#pragma unroll
    for (int n4 = 0; n4 < 4; ++n4) {
        int e = n4 * 16 + (l & 15);
#pragma unroll
        for (int r = 0; r < 4; ++r) {
            int s = w * 16 + ((l >> 4) << 2) + r;
            at_s[s * 72 + e] = f2bf(acc[n4][r] * dinv_s[s]);
        }
    }
    __syncthreads();

#pragma unroll
    for (int j = 0; j < 2; ++j) {
        int i = tid + 256 * j;
        int s = i >> 3, c = i & 7;
        bf16x8s v = *(const bf16x8s*)&at_s[s * 72 + c * 8];
        *(bf16x8s*)&attn[rowbase + (size_t)s * 1024 + c * 8] = v;
    }
}

// ---------------- launch ----------------
extern "C" void kernel_launch(void* const* d_in, const int* in_sizes, int n_in,
                              void* d_out, int out_size, void* d_ws, size_t ws_size,
                              hipStream_t stream)
{
    const float* x    = (const float*)d_in[0];
    const float* Wqkv = (const float*)d_in[1];
    const float* Wout = (const float*)d_in[2];

    char* ws = (char*)d_ws;
    size_t off = 0;
    auto alloc = [&](size_t bytes) { void* p = ws + off; off += (bytes + 255) & ~(size_t)255; return p; };
    bf16*  xb    = (bf16*)alloc((size_t)16384 * 1024 * 2);
    bf16*  wqkvb = (bf16*)alloc((size_t)3072 * 1024 * 2);
    bf16*  woutb = (bf16*)alloc((size_t)1024 * 1024 * 2);
    bf16*  Qb    = (bf16*)alloc((size_t)16384 * 1024 * 2);
    bf16*  Kb    = (bf16*)alloc((size_t)16384 * 1024 * 2);
    bf16*  Vb    = (bf16*)alloc((size_t)16384 * 1024 * 2);
    bf16*  ctxb  = (bf16*)alloc((size_t)4096 * 4096 * 2);
    float* ksum  = (float*)alloc((size_t)4096 * 64 * 4);
    bf16*  ctp   = (bf16*)alloc((size_t)4096 * 4096 * 2);
    float* ksump = (float*)alloc((size_t)4096 * 64 * 4);
    bf16*  attnb = xb;                       // xb dead after GEMM1 -> reuse
    float* outf  = (float*)d_out;

    cvt_f32_bf16<<<dim3(16384 * 1024 / 8 / 256), 256, 0, stream>>>(x, xb, 16384 * 1024 / 8);
    cvt_f32_bf16<<<dim3(3072 * 1024 / 8 / 256), 256, 0, stream>>>(Wqkv, wqkvb, 3072 * 1024 / 8);
    cvt_f32_bf16<<<dim3(1024 * 1024 / 8 / 256), 256, 0, stream>>>(Wout, woutb, 1024 * 1024 / 8);

    gemm256<0><<<dim3(12, 64), 512, 0, stream>>>(xb, wqkvb, 1024, 3072, Qb, Kb, Vb, nullptr);
    bucket_kv<<<dim3(4096), 256, 0, stream>>>(Kb, Vb, ctxb, ksum);
    cumsum_excl<<<dim3(5, 64), 256, 0, stream>>>(ctxb, ksum, ctp, ksump);
    bucket_attn<<<dim3(4096), 256, 0, stream>>>(Qb, ctp, ksump, attnb);
    gemm256<1><<<dim3(4, 64), 512, 0, stream>>>(attnb, woutb, 1024, 1024, nullptr, nullptr, nullptr, outf);
}

// Round 8
// 231.870 us; speedup vs baseline: 1.2817x; 1.1581x over previous
//
#include <hip/hip_runtime.h>
#include <hip/hip_bf16.h>
#include <math.h>

typedef __hip_bfloat16 bf16;
typedef __attribute__((ext_vector_type(4))) float f32x4;
typedef __attribute__((ext_vector_type(8))) short bf16x8s;

#define T_SEQ 4096
#define MFMA16(a, b, c) __builtin_amdgcn_mfma_f32_16x16x32_bf16(a, b, c, 0, 0, 0)
#define AS1 __attribute__((address_space(1)))
#define AS3 __attribute__((address_space(3)))

static __device__ __forceinline__ float bf2f(short u) {
    return __uint_as_float(((unsigned int)(unsigned short)u) << 16);
}
static __device__ __forceinline__ short f2bf(float f) {
    bf16 h = __float2bfloat16(f);
    union { bf16 b; short s; } c; c.b = h; return c.s;
}
static __device__ __forceinline__ int swz_f(int r) { return (r & 7) ^ (r >> 3); }

// ---------------- f32 -> bf16 conversion (vectorized) ----------------
__global__ void cvt_f32_bf16(const float* __restrict__ src, bf16* __restrict__ dst, int n8) {
    int i = blockIdx.x * 256 + threadIdx.x;
    if (i >= n8) return;
    f32x4 a = ((const f32x4*)src)[(size_t)i * 2];
    f32x4 b = ((const f32x4*)src)[(size_t)i * 2 + 1];
    union { bf16 h[8]; uint4 u; } p;
    p.h[0] = __float2bfloat16(a.x); p.h[1] = __float2bfloat16(a.y);
    p.h[2] = __float2bfloat16(a.z); p.h[3] = __float2bfloat16(a.w);
    p.h[4] = __float2bfloat16(b.x); p.h[5] = __float2bfloat16(b.y);
    p.h[6] = __float2bfloat16(b.z); p.h[7] = __float2bfloat16(b.w);
    ((uint4*)dst)[i] = p.u;
}

// ============ 256x256 tile, BK=64, 8-wave deep-pipelined bf16 GEMM ============
// MODE 0 (N-grid 12): bx<4 -> Q block: softmax(row)*0.125 in f32, write Qb bf16.
//                     bx>=4 -> KV block j=bx-4: B-panel = Wqkv rows [1024+128j,+128) u
//                     [2048+128j,+128). Epilogue computes per-(bucket,head) ksum +
//                     ctx = K^T V via LDS restage + MFMA; writes ctxb/ksum. No K/V to HBM.
// MODE 1: plain f32 output.
template<int MODE>
__global__ __launch_bounds__(512, 2)
void gemm256(const bf16* __restrict__ A, const bf16* __restrict__ Bm,
             int K, int N,
             bf16* __restrict__ out0, bf16* __restrict__ ctxb, float* __restrict__ ksum,
             float* __restrict__ outf)
{
    __shared__ __align__(16) short SMEM[65536];   // A: (buf*2+kh)*8192 ; B: +32768
    const int tid  = threadIdx.x;
    const int l    = tid & 63;
    const int wid  = tid >> 6;
    const int wr   = wid >> 2;           // 0..1
    const int wc   = wid & 3;            // 0..3

    // XCD-chunked bijective swizzle (grid % 8 == 0)
    const int nwg  = gridDim.x * gridDim.y;
    const int flat = blockIdx.y * gridDim.x + blockIdx.x;
    const int swzb = (flat & 7) * (nwg >> 3) + (flat >> 3);
    const int bx   = swzb % gridDim.x;
    const int by   = swzb / gridDim.x;
    const int brow = by * 256;
    const int bcol = bx * 256;
    const int nkt  = K >> 6;             // must be even

    const bool isKV = (MODE == 0) && (bx >= 4);
    const int  jkv  = bx - 4;
    const int  b0row = isKV ? (1024 + jkv * 128) : bcol;
    const int  b1row = isKV ? (2048 + jkv * 128) : bcol + 128;

    const int chnk = (l >> 4) ^ (((l & 15) >> 1) & 3);
    const short* baseA = &SMEM[(wr * 128 + (l & 15)) * 32 + chnk * 8];
    const short* baseB = &SMEM[32768 + (wc * 64 + (l & 15)) * 32 + chnk * 8];
#define RDA(BUF, KH, M_) (*(const bf16x8s*)(baseA + (BUF) * 16384 + (KH) * 8192 + (M_) * 512))
#define RDB(BUF, KH, N_) (*(const bf16x8s*)(baseB + (BUF) * 16384 + (KH) * 8192 + (N_) * 512))

    const int srow = tid >> 2;
    const int scs  = (tid & 3) ^ ((srow >> 1) & 3);
    const bf16* gA0 = A  + (size_t)(brow + srow) * K + scs * 8;
    const bf16* gA1 = A  + (size_t)(brow + 128 + srow) * K + scs * 8;
    const bf16* gB0 = Bm + (size_t)(b0row + srow) * K + scs * 8;
    const bf16* gB1 = Bm + (size_t)(b1row + srow) * K + scs * 8;
#define GLL(PTR, KH, BUF, ISB, EXTRA)                                             \
    __builtin_amdgcn_global_load_lds((const AS1 void*)((PTR) + (KH) * 32),        \
        (AS3 void*)&SMEM[(ISB) * 32768 + ((BUF) * 2 + (KH)) * 8192 + (EXTRA) + tid * 8], 16, 0, 0)

    f32x4 acc[8][4];
#pragma unroll
    for (int m = 0; m < 8; ++m)
#pragma unroll
        for (int n = 0; n < 4; ++n) acc[m][n] = (f32x4){0.f, 0.f, 0.f, 0.f};

    GLL(gA0, 0, 0, 0, 0);    GLL(gA1, 0, 0, 0, 4096);
    GLL(gB0, 0, 0, 1, 0);    GLL(gB1, 0, 0, 1, 4096);
    GLL(gA0, 1, 0, 0, 0);    GLL(gA1, 1, 0, 0, 4096);
    GLL(gB0, 1, 0, 1, 0);    GLL(gB1, 1, 0, 1, 4096);
    asm volatile("s_waitcnt vmcnt(4)" ::: "memory");
    __builtin_amdgcn_s_barrier();

    const bf16 *pA0 = gA0 + 64, *pA1 = gA1 + 64, *pB0 = gB0 + 64, *pB1 = gB1 + 64;

#define MFMA_BLOCK(ACCOFF)                                                        \
    __builtin_amdgcn_s_barrier();                                                 \
    asm volatile("s_waitcnt lgkmcnt(0)" ::: "memory");                            \
    __builtin_amdgcn_sched_barrier(0);                                            \
    __builtin_amdgcn_s_setprio(1);                                                \
    _Pragma("unroll")                                                             \
    for (int m = 0; m < 4; ++m)                                                   \
        _Pragma("unroll")                                                         \
        for (int n = 0; n < 4; ++n)                                               \
            acc[m + (ACCOFF)][n] = MFMA16(afr[m], bfr[n], acc[m + (ACCOFF)][n]);  \
    __builtin_amdgcn_s_setprio(0);                                                \
    __builtin_amdgcn_s_barrier();

#define BODY(CUR, NXT, TT)                                                        \
    {                                                                             \
        const bool pf = ((TT) + 1 < nkt);                                         \
        bf16x8s afr[4], bfr[4];                                                   \
        _Pragma("unroll") for (int n = 0; n < 4; ++n) bfr[n] = RDB(CUR, 0, n);    \
        _Pragma("unroll") for (int m = 0; m < 4; ++m) afr[m] = RDA(CUR, 0, m);    \
        if (pf) { GLL(pA0, 0, NXT, 0, 0); GLL(pA1, 0, NXT, 0, 4096); }            \
        MFMA_BLOCK(0)                                                             \
        _Pragma("unroll") for (int m = 0; m < 4; ++m) afr[m] = RDA(CUR, 0, m + 4);\
        if (pf) { GLL(pB0, 0, NXT, 1, 0); GLL(pB1, 0, NXT, 1, 4096); }            \
        asm volatile("s_waitcnt vmcnt(4)" ::: "memory");                          \
        MFMA_BLOCK(4)                                                             \
        _Pragma("unroll") for (int n = 0; n < 4; ++n) bfr[n] = RDB(CUR, 1, n);    \
        _Pragma("unroll") for (int m = 0; m < 4; ++m) afr[m] = RDA(CUR, 1, m);    \
        if (pf) { GLL(pA0, 1, NXT, 0, 0); GLL(pA1, 1, NXT, 0, 4096); }            \
        MFMA_BLOCK(0)                                                             \
        _Pragma("unroll") for (int m = 0; m < 4; ++m) afr[m] = RDA(CUR, 1, m + 4);\
        if (pf) { GLL(pB0, 1, NXT, 1, 0); GLL(pB1, 1, NXT, 1, 4096); }            \
        asm volatile("s_waitcnt vmcnt(4)" ::: "memory");                          \
        MFMA_BLOCK(4)                                                             \
        pA0 += 64; pA1 += 64; pB0 += 64; pB1 += 64;                               \
    }

    for (int t = 0; t < nkt; t += 2) {
        BODY(0, 1, t)
        BODY(1, 0, t + 1)
    }

    if (MODE == 1) {
#pragma unroll
        for (int m = 0; m < 8; ++m) {
            int row = brow + wr * 128 + m * 16 + ((l >> 4) << 2);
#pragma unroll
            for (int n = 0; n < 4; ++n) {
                int col = bcol + wc * 64 + n * 16 + (l & 15);
#pragma unroll
                for (int r = 0; r < 4; ++r)
                    outf[(size_t)(row + r) * N + col] = acc[m][n][r];
            }
        }
    } else if (!isKV) {
        // ---- Q epilogue: f32 row-softmax over the 64-wide head (this wave's wc) ----
#pragma unroll
        for (int m = 0; m < 8; ++m) {
            int row = brow + wr * 128 + m * 16 + ((l >> 4) << 2);
#pragma unroll
            for (int r = 0; r < 4; ++r) {
                float v0 = acc[m][0][r], v1 = acc[m][1][r], v2 = acc[m][2][r], v3 = acc[m][3][r];
                float mx = fmaxf(fmaxf(v0, v1), fmaxf(v2, v3));
#pragma unroll
                for (int off = 8; off; off >>= 1) mx = fmaxf(mx, __shfl_xor(mx, off));
                float e0 = __expf(v0 - mx), e1 = __expf(v1 - mx);
                float e2 = __expf(v2 - mx), e3 = __expf(v3 - mx);
                float sm = e0 + e1 + e2 + e3;
#pragma unroll
                for (int off = 8; off; off >>= 1) sm += __shfl_xor(sm, off);
                float inv = 0.125f / sm;
                size_t rr = (size_t)(row + r);
                int cb = bcol + wc * 64 + (l & 15);
                out0[rr * 1024 + cb]      = __float2bfloat16(e0 * inv);
                out0[rr * 1024 + cb + 16] = __float2bfloat16(e1 * inv);
                out0[rr * 1024 + cb + 32] = __float2bfloat16(e2 * inv);
                out0[rr * 1024 + cb + 48] = __float2bfloat16(e3 * inv);
            }
        }
    } else {
        // ---- KV epilogue: ctx + ksum for 8 (bucket,head) units, no K/V to HBM ----
        // step 1: scatter exp(K) / V fragments into swizzled [d][s] LDS per unit
        const int hl = wc & 1;                       // head_local (K: wc 0,1; V: wc 2,3)
        short* side = (short*)SMEM + ((wc >= 2) ? 32768 : 0);
#pragma unroll
        for (int m = 0; m < 8; ++m) {
            const int ubase = wr * 16384 + (m >> 2) * 8192 + hl * 4096;  // unit*4096
#pragma unroll
            for (int n = 0; n < 4; ++n) {
                int d = n * 16 + (l & 15);
#pragma unroll
                for (int r = 0; r < 4; ++r) {
                    int s = (m & 3) * 16 + ((l >> 4) << 2) + r;
                    float v = acc[m][n][r];
                    if (wc < 2) v = __expf(v);
                    side[ubase + d * 64 + ((((s >> 3)) ^ swz_f(d)) << 3) + (s & 7)] = f2bf(v);
                }
            }
        }
        __syncthreads();

        // step 2: wave wid owns unit wid = bl*2+hl
        const int bl = wid >> 1, hu = wid & 1;
        const int gr0 = brow + bl * 64;
        const int bb  = gr0 >> 12;
        const int nb  = (gr0 & 4095) >> 6;
        const int hh  = jkv * 2 + hu;
        const size_t bid = (size_t)(bb * 16 + hh) * 64 + nb;
        const short* k_u = (const short*)SMEM + wid * 4096;
        const short* v_u = (const short*)SMEM + 32768 + wid * 4096;

        // ksum: lane = d
        {
            float s = 0.f;
#pragma unroll
            for (int c = 0; c < 8; ++c) {
                bf16x8s kk = *(const bf16x8s*)&k_u[l * 64 + ((c ^ swz_f(l)) << 3)];
#pragma unroll
                for (int u = 0; u < 8; ++u) s += bf2f(((short*)&kk)[u]);
            }
            ksum[bid * 64 + l] = s;
        }

        // ctx = K^T V : full 64x64 per wave (32 MFMA)
        f32x4 a16[4][4];
#pragma unroll
        for (int m = 0; m < 4; ++m)
#pragma unroll
            for (int n = 0; n < 4; ++n) a16[m][n] = (f32x4){0.f, 0.f, 0.f, 0.f};
#pragma unroll
        for (int kk = 0; kk < 2; ++kk) {
            const int cc = kk * 4 + (l >> 4);
            bf16x8s af[4], bf[4];
#pragma unroll
            for (int m = 0; m < 4; ++m) {
                int rA = m * 16 + (l & 15);
                af[m] = *(const bf16x8s*)&k_u[rA * 64 + ((cc ^ swz_f(rA)) << 3)];
                bf[m] = *(const bf16x8s*)&v_u[rA * 64 + ((cc ^ swz_f(rA)) << 3)];
            }
#pragma unroll
            for (int m = 0; m < 4; ++m)
#pragma unroll
                for (int n = 0; n < 4; ++n)
                    a16[m][n] = MFMA16(af[m], bf[n], a16[m][n]);
        }
        // write record [e*64 + d] (= ctx[d][e]); 4 consecutive d per store
        bf16* rec = ctxb + bid * 4096;
#pragma unroll
        for (int m = 0; m < 4; ++m) {
            int d0 = m * 16 + ((l >> 4) << 2);
#pragma unroll
            for (int n = 0; n < 4; ++n) {
                int e = n * 16 + (l & 15);
                ushort4 o;
                o.x = (ushort)f2bf(a16[m][n][0]); o.y = (ushort)f2bf(a16[m][n][1]);
                o.z = (ushort)f2bf(a16[m][n][2]); o.w = (ushort)f2bf(a16[m][n][3]);
                *(ushort4*)&rec[e * 64 + d0] = o;
            }
        }
    }
#undef RDA
#undef RDB
#undef GLL
#undef MFMA_BLOCK
#undef BODY
}

// ---------------- exclusive cumsum over buckets ----------------
__global__ void cumsum_excl(const bf16* __restrict__ ctxb, const float* __restrict__ ksum,
                            bf16* __restrict__ ctp, float* __restrict__ ksump)
{
    const int bh = blockIdx.y;
    if (blockIdx.x == 4) {
        int d = threadIdx.x;
        if (d >= 64) return;
        float run = 0.f;
        for (int j = 0; j < 64; ++j) {
            size_t idx = (size_t)(bh * 64 + j) * 64 + d;
            float v = ksum[idx];
            ksump[idx] = run;
            run += v;
        }
        return;
    }
    int e0 = (blockIdx.x * 256 + threadIdx.x) * 4;
    float r0 = 0.f, r1 = 0.f, r2 = 0.f, r3 = 0.f;
    for (int j = 0; j < 64; ++j) {
        size_t idx = (size_t)(bh * 64 + j) * 4096 + e0;
        ushort4 v = *(const ushort4*)&ctxb[idx];
        ushort4 o;
        o.x = (ushort)f2bf(r0); o.y = (ushort)f2bf(r1);
        o.z = (ushort)f2bf(r2); o.w = (ushort)f2bf(r3);
        *(ushort4*)&ctp[idx] = o;
        r0 += bf2f((short)v.x); r1 += bf2f((short)v.y);
        r2 += bf2f((short)v.z); r3 += bf2f((short)v.w);
    }
}

// ---------------- den + attn = q @ ctx * Dinv (q pre-softmaxed in GEMM1) ----------------
__global__ __launch_bounds__(256)
void bucket_attn(const bf16* __restrict__ Qb, const bf16* __restrict__ ctp,
                 const float* __restrict__ ksump, bf16* __restrict__ attn)
{
    __shared__ __align__(16) short q_bf[64 * 64];
    __shared__ __align__(16) short ct_bf[64 * 64];
    __shared__ __align__(16) short at_s[64 * 72];
    __shared__ float dinv_s[64];
    __shared__ float ksum_s[64];
    const int bid = blockIdx.x;
    const int bh = bid >> 6, n = bid & 63;
    const int b = bh >> 4, h = bh & 15;
    const size_t rowbase = (size_t)(b * T_SEQ + n * 64) * 1024 + h * 64;
    const int tid = threadIdx.x;
    const int l = tid & 63, w = tid >> 6;

#pragma unroll
    for (int j = 0; j < 2; ++j) {
        int i = tid + 256 * j;
        int e = i >> 3, dc = i & 7;
        bf16x8s cv = *(const bf16x8s*)&ctp[(size_t)bid * 4096 + e * 64 + dc * 8];
        *(bf16x8s*)&ct_bf[e * 64 + ((dc ^ swz_f(e)) << 3)] = cv;
    }
    if (tid < 64) ksum_s[tid] = ksump[(size_t)bid * 64 + tid];
    __syncthreads();

    // den reduce only (softmax already applied in GEMM1)
#pragma unroll
    for (int i = 0; i < 16; ++i) {
        int s = w * 16 + i;
        float qv = bf2f(*(const short*)&Qb[rowbase + (size_t)s * 1024 + l]);
        float dp = qv * ksum_s[l];
#pragma unroll
        for (int off = 32; off; off >>= 1) dp += __shfl_xor(dp, off);
        if (l == 0) dinv_s[s] = 1.f / fmaxf(dp, 1e-6f);
        q_bf[s * 64 + ((((l >> 3)) ^ swz_f(s)) << 3) + (l & 7)] = f2bf(qv);
    }
    __syncthreads();

    f32x4 acc[4];
#pragma unroll
    for (int i = 0; i < 4; ++i) acc[i] = (f32x4){0.f, 0.f, 0.f, 0.f};
    bf16x8s afr[2], bfr[2][4];
#pragma unroll
    for (int kk = 0; kk < 2; ++kk) {
        int cc = kk * 4 + (l >> 4);
        int r = w * 16 + (l & 15);
        afr[kk] = *(const bf16x8s*)&q_bf[r * 64 + ((cc ^ swz_f(r)) << 3)];
#pragma unroll
        for (int n4 = 0; n4 < 4; ++n4) {
            int e = n4 * 16 + (l & 15);
            bfr[kk][n4] = *(const bf16x8s*)&ct_bf[e * 64 + ((cc ^ swz_f(e)) << 3)];
        }
    }
#pragma unroll
    for (int kk = 0; kk < 2; ++kk)
#pragma unroll
        for (int n4 = 0; n4 < 4; ++n4)
            acc[n4] = MFMA16(afr[kk], bfr[kk][n4], acc[n4]);

#pragma unroll
    for (int n4 = 0; n4 < 4; ++n4) {
        int e = n4 * 16 + (l & 15);
#pragma unroll
        for (int r = 0; r < 4; ++r) {
            int s = w * 16 + ((l >> 4) << 2) + r;
            at_s[s * 72 + e] = f2bf(acc[n4][r] * dinv_s[s]);
        }
    }
    __syncthreads();

#pragma unroll
    for (int j = 0; j < 2; ++j) {
        int i = tid + 256 * j;
        int s = i >> 3, c = i & 7;
        bf16x8s v = *(const bf16x8s*)&at_s[s * 72 + c * 8];
        *(bf16x8s*)&attn[rowbase + (size_t)s * 1024 + c * 8] = v;
    }
}

// ---------------- launch ----------------
extern "C" void kernel_launch(void* const* d_in, const int* in_sizes, int n_in,
                              void* d_out, int out_size, void* d_ws, size_t ws_size,
                              hipStream_t stream)
{
    const float* x    = (const float*)d_in[0];
    const float* Wqkv = (const float*)d_in[1];
    const float* Wout = (const float*)d_in[2];

    char* ws = (char*)d_ws;
    size_t off = 0;
    auto alloc = [&](size_t bytes) { void* p = ws + off; off += (bytes + 255) & ~(size_t)255; return p; };
    bf16*  xb    = (bf16*)alloc((size_t)16384 * 1024 * 2);
    bf16*  wqkvb = (bf16*)alloc((size_t)3072 * 1024 * 2);
    bf16*  woutb = (bf16*)alloc((size_t)1024 * 1024 * 2);
    bf16*  Qb    = (bf16*)alloc((size_t)16384 * 1024 * 2);
    bf16*  ctxb  = (bf16*)alloc((size_t)4096 * 4096 * 2);
    float* ksum  = (float*)alloc((size_t)4096 * 64 * 4);
    bf16*  ctp   = (bf16*)alloc((size_t)4096 * 4096 * 2);
    float* ksump = (float*)alloc((size_t)4096 * 64 * 4);
    bf16*  attnb = xb;                       // xb dead after GEMM1 -> reuse
    float* outf  = (float*)d_out;

    cvt_f32_bf16<<<dim3(16384 * 1024 / 8 / 256), 256, 0, stream>>>(x, xb, 16384 * 1024 / 8);
    cvt_f32_bf16<<<dim3(3072 * 1024 / 8 / 256), 256, 0, stream>>>(Wqkv, wqkvb, 3072 * 1024 / 8);
    cvt_f32_bf16<<<dim3(1024 * 1024 / 8 / 256), 256, 0, stream>>>(Wout, woutb, 1024 * 1024 / 8);

    gemm256<0><<<dim3(12, 64), 512, 0, stream>>>(xb, wqkvb, 1024, 3072, Qb, ctxb, ksum, nullptr);
    cumsum_excl<<<dim3(5, 64), 256, 0, stream>>>(ctxb, ksum, ctp, ksump);
    bucket_attn<<<dim3(4096), 256, 0, stream>>>(Qb, ctp, ksump, attnb);
    gemm256<1><<<dim3(4, 64), 512, 0, stream>>>(attnb, woutb, 1024, 1024, nullptr, nullptr, nullptr, outf);
}